// Round 18
// baseline (441.763 us; speedup 1.0000x reference)
//
#include <hip/hip_runtime.h>

typedef __attribute__((ext_vector_type(8))) short short8;
typedef __attribute__((ext_vector_type(4))) float f32x4;
typedef unsigned int u32;

#define CIN   128
#define COUT  256
#define H     112
#define W     112
#define OH    110
#define OW    110
#define KHW   9
#define TH    8
#define TW    32
#define IWW   34              // TW+2
#define NPIX  340             // 10*34
#define XB    (NPIX*8*16)     // 43520 B per x half-buffer (2720 16B slots)
#define WBUF  32768           // 256 cout * 8 slots * 16B per w stage buffer
#define ROWB  (IWW*128)       // 4352: LDS bytes per x row

__device__ __forceinline__ short f2b(float f) {
  unsigned u = __builtin_bit_cast(unsigned, f);
  unsigned r = (u + 0x7FFFu + ((u >> 16) & 1u)) >> 16;  // RNE
  return (short)r;
}

__device__ __forceinline__ void gload16(const void* g, void* l) {
  __builtin_amdgcn_global_load_lds(
      (const __attribute__((address_space(1))) u32*)g,
      (__attribute__((address_space(3))) u32*)l, 16, 0, 0);
}

// R18: 1 block/CU, 4 waves, 512 regs/wave (launch_bounds(256,1)).
// Wave tile 128 cout x 128 px -> acc[8][8] = 256 AGPR; 16 LDS reads feed 64
// MFMAs (4 B/MFMA vs 6 before) -> LDS/CU/tap 1536 cyc < MFMA 2483 cyc, and
// ~130 spare VGPRs let the compiler pipeline reads under MFMA clusters.
// x LDS (R13 layout, proven 0-conflict): byte(p,G)=p*128+((G^(ix&7))<<4),
// ix=p%34 (row-invariant key: kh/row walks = +4352 immediates). TWO x half
// buffers; half-1 DMA dribbled in 6 chunks under taps 2..7 (each chunk's
// drain overlaps that tap's MFMA cluster). w LDS: c*128+((G^(c&7))<<4),
// double-buffered per tap. DMA: linear dest, source-preswizzled (m173);
// OOB lanes -> zero page (wave-uniform-base contract); prefix tails only.

template<bool XT, bool WT>
__global__ __launch_bounds__(256, 1)
void conv_main(const float* __restrict__ x, const float* __restrict__ wgt,
               const short* __restrict__ wt, const short* __restrict__ xt,
               const short* __restrict__ zp, float* __restrict__ out) {
  __shared__ __align__(16) char smem[2*XB + 2*WBUF];   // 152576 B
  char* sx = smem;                  // x half-buffers [2][XB]
  char* sw = smem + 2*XB;           // w stage buffers [2][WBUF]

  const int tid = threadIdx.x;

  // XCD-chunked bijective swizzle (1792 % 8 == 0)
  const int nb  = gridDim.x;
  const int swz = (blockIdx.x & 7) * (nb >> 3) + (blockIdx.x >> 3);
  const int b    = swz / 56;             // 4 tw * 14 th
  const int rem  = swz - b * 56;
  const int t_w  = rem / 14;
  const int t_h  = rem - t_w * 14;
  const int h0 = t_h * TH, w0 = t_w * TW;

  // full x-half stage (used for half 0 prologue / fallback path)
  auto stage_x = [&](int hh) {
    if (XT) {
      const short* xtb = xt + (size_t)b * (H*W*CIN);
      #pragma unroll
      for (int it = 0; it < 11; ++it) {
        int u = it*256 + tid;            // 2720 slots
        if (u < 8*NPIX) {                // prefix tail: safe
          int p = u >> 3;
          int iy = p / IWW, ix = p - iy * IWW;
          int Geff = (u & 7) ^ (ix & 7);
          int gy = h0 + iy, gx = w0 + ix;
          const short* src = (gy < H && gx < W)
              ? xtb + ((size_t)gy*W + gx)*CIN + hh*64 + Geff*8
              : zp;
          gload16(src, sx + hh*XB + u*16);
        }
      }
    } else {
      const float* xh = x + (size_t)b * CIN * (H*W) + (size_t)(hh*64) * (H*W);
      for (int u = tid; u < 8 * NPIX; u += 256) {
        int G = u / NPIX, p = u - G * NPIX;
        int iy = p / IWW, ix = p - iy * IWW;
        int gy = h0 + iy, gx = w0 + ix;
        short8 v = {0,0,0,0,0,0,0,0};
        if (gy < H && gx < W) {
          const float* s = xh + (size_t)(G*8) * (H*W) + gy * W + gx;
          #pragma unroll
          for (int j = 0; j < 8; ++j) v[j] = f2b(s[j * (H*W)]);
        }
        *(short8*)(sx + hh*XB + p*128 + ((G ^ (ix & 7)) << 4)) = v;
      }
    }
  };

  // chunked x-half-1 stage: chunk c covers slots [c*454, min((c+1)*454,2720))
  auto stage_x1_chunk = [&](int c) {
    if (!XT) return;                     // fallback stages half-1 at once
    const short* xtb = xt + (size_t)b * (H*W*CIN);
    const int lim = (c == 5) ? 2720 : (c + 1) * 454;
    #pragma unroll
    for (int q = 0; q < 2; ++q) {
      int u = c*454 + q*256 + tid;
      if (u < lim) {                     // prefix within wave: safe
        int p = u >> 3;
        int iy = p / IWW, ix = p - iy * IWW;
        int Geff = (u & 7) ^ (ix & 7);
        int gy = h0 + iy, gx = w0 + ix;
        const short* src = (gy < H && gx < W)
            ? xtb + ((size_t)gy*W + gx)*CIN + 64 + Geff*8
            : zp;
        gload16(src, sx + XB + u*16);
      }
    }
  };

  // w staging lane constants
  int wgoff[8];
  #pragma unroll
  for (int it = 0; it < 8; ++it) {
    int slot = it*256 + tid;             // 2048 slots of 16B
    int c = slot >> 3, gsw = (slot & 7) ^ (c & 7);
    wgoff[it] = c * CIN + gsw * 8;
  }
  auto stage_w = [&](int tap, int hh, int buf) {
    if (WT) {
      const short* base = wt + tap*(COUT*CIN) + hh*64;
      #pragma unroll
      for (int it = 0; it < 8; ++it)
        gload16(base + wgoff[it], sw + buf*WBUF + (it*256 + tid)*16);
    } else {
      #pragma unroll
      for (int it = 0; it < 8; ++it) {
        int slot = it*256 + tid;
        int c = slot >> 3, gsw = (slot & 7) ^ (c & 7);
        short8 v;
        #pragma unroll
        for (int j = 0; j < 8; ++j) {
          int cin = hh*64 + gsw*8 + j;
          v[j] = f2b(wgt[c*(CIN*KHW) + cin*KHW + tap]);
        }
        *(short8*)(sw + buf*WBUF + slot*16) = v;
      }
    }
  };

  const int lane = tid & 63;
  const int wid  = tid >> 6;      // 0..3
  const int wm = wid & 1;         // cout half: [wm*128, +128)
  const int wn = wid >> 1;        // px row half: rows [wn*4, +4)
  const int l15 = lane & 15;
  const int kgrp = lane >> 4;     // 0..3
  const int l7 = l15 & 7;

  // base addresses (all loop reads = base + immediate)
  const char* abase[2];
  const char* bbase[2][3];        // half-0; +XB for half-1
  #pragma unroll
  for (int s = 0; s < 2; ++s) {
    const int g = s*4 + kgrp;
    abase[s] = sw + (wm*128 + l15)*128 + ((g ^ l7) << 4);
    #pragma unroll
    for (int kw = 0; kw < 3; ++kw) {
      const int lk = l15 + kw;
      bbase[s][kw] = sx + (4*wn)*ROWB + lk*128 + ((g ^ (lk & 7)) << 4);
    }
  }

  f32x4 acc[8][8] = {};

  stage_x(0);
  stage_w(0, 0, 0);
  __syncthreads();

  #pragma unroll 1
  for (int hh = 0; hh < 2; ++hh) {
    const char* bbh0 = bbase[0][0] + hh*XB;   // fold hh offset once
    const int dxb = (int)(bbh0 - bbase[0][0]);
    #pragma unroll
    for (int tap9 = 0; tap9 < 9; ++tap9) {
      const int kh = tap9 / 3, kw = tap9 - (tap9/3)*3;
      const int wboff = ((hh + tap9) & 1) * WBUF;

      // issue next-stage w DMA (skip at the very last stage)
      if (!(hh == 1 && tap9 == 8)) {
        const int ntap = (tap9 == 8) ? 0 : tap9 + 1;
        const int nhh  = (tap9 == 8) ? hh + 1 : hh;
        stage_w(ntap, nhh, ((hh + tap9) & 1) ^ 1);
      }
      // dribble x half-1 DMA under taps 2..7 of half 0
      if (hh == 0 && tap9 >= 2 && tap9 <= 7) stage_x1_chunk(tap9 - 2);

      #pragma unroll
      for (int s = 0; s < 2; ++s) {
        short8 a[8];
        #pragma unroll
        for (int mi = 0; mi < 8; ++mi)
          a[mi] = *(const short8*)(abase[s] + wboff + mi*2048);
        short8 bf[8];
        #pragma unroll
        for (int ni = 0; ni < 8; ++ni)
          bf[ni] = *(const short8*)(bbase[s][kw] + dxb
                       + (kh + (ni >> 1))*ROWB + (ni & 1)*2048);
        #pragma unroll
        for (int mi = 0; mi < 8; ++mi)
          #pragma unroll
          for (int ni = 0; ni < 8; ++ni)
            acc[mi][ni] = __builtin_amdgcn_mfma_f32_16x16x32_bf16(
                a[mi], bf[ni], acc[mi][ni], 0, 0, 0);
      }

      if (hh == 0 && tap9 == 8 && !XT) {
        __syncthreads();
        stage_x(1);                 // fallback: stage half-1 in one go
        __syncthreads();
      } else {
        __syncthreads();            // w(next) + x-chunk drained; buf swap safe
      }
    }
  }

  // ---- epilogue: C layout col=l15 (px), row=4*kgrp+r (cout) [m89] ----
  float* ob = out + (size_t)b * COUT * (OH*OW);
  #pragma unroll
  for (int ni = 0; ni < 8; ++ni) {
    int oh = h0 + 4*wn + (ni >> 1);
    int ow = w0 + (ni & 1)*16 + l15;
    if (oh < OH && ow < OW) {
      #pragma unroll
      for (int mi = 0; mi < 8; ++mi) {
        #pragma unroll
        for (int r = 0; r < 4; ++r) {
          int cout = wm*128 + mi*16 + kgrp*4 + r;
          ob[(size_t)cout*(OH*OW) + oh*OW + ow] = acc[mi][ni][r];
        }
      }
    }
  }
}

// one-time weight transpose+cvt: wt[tap][cout][cin] bf16; also zeros the
// 256-B zero page that follows wt in the workspace.
__global__ void wprep(const float* __restrict__ wgt, short* __restrict__ wt,
                      short* __restrict__ zp) {
  int idx = blockIdx.x * 256 + threadIdx.x;
  if (idx < 128) zp[idx] = 0;
  if (idx >= KHW*COUT*CIN) return;
  int khw  = idx / (COUT*CIN);
  int rem  = idx - khw*(COUT*CIN);
  int cout = rem >> 7, cin = rem & 127;
  wt[idx] = f2b(wgt[cout*(CIN*KHW) + cin*KHW + khw]);
}

// one-time x transpose+cvt: xt[b][h][w][cin] bf16, via padded LDS tile.
__global__ __launch_bounds__(256)
void xprep(const float* __restrict__ x, short* __restrict__ xt) {
  __shared__ short lsh[CIN * 113];   // 28928 B
  const int bh = blockIdx.x;
  const int b = bh / H, h = bh - b * H;
  const float* src = x + ((size_t)b * CIN * H + h) * W;
  for (int u = threadIdx.x; u < CIN * W; u += 256) {
    int c = u / W, w = u - c * W;
    lsh[c * 113 + w] = f2b(src[(size_t)c * (H*W) + w]);
  }
  __syncthreads();
  short* dst = xt + (size_t)bh * (W * CIN);
  for (int o = threadIdx.x; o < W * CIN / 8; o += 256) {   // 1792
    int w = o >> 4, s = o & 15;
    short8 v;
    #pragma unroll
    for (int j = 0; j < 8; ++j) v[j] = lsh[(s*8 + j) * 113 + w];
    *(short8*)(dst + o * 8) = v;
  }
}

extern "C" void kernel_launch(void* const* d_in, const int* in_sizes, int n_in,
                              void* d_out, int out_size, void* d_ws, size_t ws_size,
                              hipStream_t stream) {
  const float* x   = (const float*)d_in[0];
  const float* wgt = (const float*)d_in[1];
  float* out = (float*)d_out;
  const size_t wt_bytes = (size_t)(KHW*COUT*CIN) * sizeof(short);   // 589824
  const size_t zp_bytes = 256;
  const size_t xt_bytes = (size_t)32 * H * W * CIN * sizeof(short); // 102.76 MB
  dim3 grid(1792);   // 4 tw x 14 th x 32 b
  if (ws_size >= wt_bytes + zp_bytes + xt_bytes) {
    short* wt = (short*)d_ws;
    short* zp = (short*)((char*)d_ws + wt_bytes);
    short* xt = (short*)((char*)d_ws + wt_bytes + zp_bytes);
    wprep<<<(KHW*COUT*CIN + 255)/256, 256, 0, stream>>>(wgt, wt, zp);
    xprep<<<32 * H, 256, 0, stream>>>(x, xt);
    conv_main<true, true><<<grid, 256, 0, stream>>>(x, wgt, wt, xt, zp, out);
  } else if (ws_size >= wt_bytes + zp_bytes) {
    short* wt = (short*)d_ws;
    short* zp = (short*)((char*)d_ws + wt_bytes);
    wprep<<<(KHW*COUT*CIN + 255)/256, 256, 0, stream>>>(wgt, wt, zp);
    conv_main<false, true><<<grid, 256, 0, stream>>>(x, wgt, wt, nullptr, zp, out);
  } else {
    conv_main<false, false><<<grid, 256, 0, stream>>>(x, wgt, nullptr, nullptr, nullptr, out);
  }
}

// Round 19
// 339.742 us; speedup vs baseline: 1.3003x; 1.3003x over previous
//
#include <hip/hip_runtime.h>

typedef __attribute__((ext_vector_type(8))) short short8;
typedef __attribute__((ext_vector_type(4))) float f32x4;
typedef unsigned int u32;

#define CIN   128
#define COUT  256
#define H     112
#define W     112
#define OH    110
#define OW    110
#define KHW   9
#define TH    8
#define TW    32
#define IWW   34              // TW+2
#define NPIX  340             // 10*34
#define XB    (NPIX*8*16)     // 43520 B: x half-tile, 2720 16B slots
#define WB    16384           // w tap-half: 128 cout * 8 slots * 16B
#define ROWB  (IWW*128)       // 4352: LDS bytes per x row

__device__ __forceinline__ short f2b(float f) {
  unsigned u = __builtin_bit_cast(unsigned, f);
  unsigned r = (u + 0x7FFFu + ((u >> 16) & 1u)) >> 16;  // RNE
  return (short)r;
}

__device__ __forceinline__ void gload16(const void* g, void* l) {
  __builtin_amdgcn_global_load_lds(
      (const __attribute__((address_space(1))) u32*)g,
      (__attribute__((address_space(3))) u32*)l, 16, 0, 0);
}

// R19 = R13 + ZERO-REGISTER cross-barrier B-prefetch:
//  - MFMA clusters ni-major so bf[ni] dies after its 4 MFMAs;
//  - next stage's B(s0) reads issued into the SAME bf[] AFTER cluster1,
//    BEFORE __syncthreads (x buffer is stable across a half's 9 taps, so
//    only A(w) reads actually need the barrier). The barrier's implicit
//    lgkmcnt(0) completes them into regs; stage entry pays only 4 A-reads.
//  - st==8 special case: prefetch AFTER the x half-1 restage barriers.
// Everything else = R13: 2 waves/SIMD, acc[4][8] (252/256 regs), x LDS
// byte(p,G)=p*128+((G^(ix&7))<<4) row-invariant key (0-conflict, imm walks),
// w LDS c*128+((G^(c&7))<<4), DMA linear dest + source-preswizzle (m173),
// OOB -> zero page, XCD-chunked bijective block swizzle.

template<bool XT, bool WT>
__global__ __launch_bounds__(256, 2)
void conv_main(const float* __restrict__ x, const float* __restrict__ wgt,
               const short* __restrict__ wt, const short* __restrict__ xt,
               const short* __restrict__ zp, float* __restrict__ out) {
  __shared__ __align__(16) char smem[XB + 2*WB];   // 76288 B -> 2 blocks/CU
  char* sx = smem;
  char* sw = smem + XB;

  const int tid = threadIdx.x;

  // XCD-chunked bijective swizzle (3584 % 8 == 0)
  const int nb  = gridDim.x;
  const int swz = (blockIdx.x & 7) * (nb >> 3) + (blockIdx.x >> 3);
  const int b    = swz / 112;            // 2 cblk * 4 tw * 14 th
  const int rem  = swz - b * 112;
  const int cblk = rem / 56;
  const int rem2 = rem - cblk * 56;
  const int t_w  = rem2 / 14;
  const int t_h  = rem2 - t_w * 14;
  const int h0 = t_h * TH, w0 = t_w * TW;

  auto stage_x = [&](int hh) {
    if (XT) {
      const short* xtb = xt + (size_t)b * (H*W*CIN);
      #pragma unroll
      for (int it = 0; it < 11; ++it) {
        int u = it*256 + tid;            // slot index, 2720 total
        if (u < 8*NPIX) {                // prefix-masked tail only: safe
          int p = u >> 3;                // pixel 0..339
          int iy = p / IWW, ix = p - iy * IWW;
          int Geff = (u & 7) ^ (ix & 7); // pre-swizzled source fragment
          int gy = h0 + iy, gx = w0 + ix;
          const short* src = (gy < H && gx < W)
              ? xtb + ((size_t)gy*W + gx)*CIN + hh*64 + Geff*8
              : zp;                      // OOB -> zero page (per-lane src ok)
          gload16(src, sx + u*16);
        }
      }
    } else {
      const float* xh = x + (size_t)b * CIN * (H*W) + (size_t)(hh*64) * (H*W);
      for (int u = tid; u < 8 * NPIX; u += 256) {
        int G = u / NPIX, p = u - G * NPIX;
        int iy = p / IWW, ix = p - iy * IWW;
        int gy = h0 + iy, gx = w0 + ix;
        short8 v = {0,0,0,0,0,0,0,0};
        if (gy < H && gx < W) {
          const float* s = xh + (size_t)(G*8) * (H*W) + gy * W + gx;
          #pragma unroll
          for (int j = 0; j < 8; ++j) v[j] = f2b(s[j * (H*W)]);
        }
        *(short8*)(sx + p*128 + ((G ^ (ix & 7)) << 4)) = v;
      }
    }
  };

  auto stage_w = [&](int st, int buf) {
    int hh = st / 9, tap = st - hh * 9;
    if (WT) {
      const short* base = wt + (size_t)tap * (COUT*CIN)
                             + (size_t)(cblk*128) * CIN + hh * 64;
      #pragma unroll
      for (int it = 0; it < 4; ++it) {
        int slot = it * 256 + tid;            // 1024 slots of 16B
        int c = slot >> 3, gsw = (slot & 7) ^ (c & 7);
        gload16(base + c * CIN + gsw * 8, sw + buf*WB + slot * 16);
      }
    } else {
      #pragma unroll
      for (int it = 0; it < 4; ++it) {
        int slot = it * 256 + tid;
        int c = slot >> 3, gsw = (slot & 7) ^ (c & 7);
        int cout = cblk*128 + c;
        short8 v;
        #pragma unroll
        for (int j = 0; j < 8; ++j) {
          int cin = hh*64 + gsw*8 + j;
          v[j] = f2b(wgt[cout*(CIN*KHW) + cin*KHW + tap]);
        }
        *(short8*)(sw + buf*WB + slot * 16) = v;
      }
    }
  };

  const int lane = tid & 63;
  const int wid  = tid >> 6;      // 0..3
  const int wm = wid >> 1;        // 0..1 -> couts [wm*64, +64) of block's 128
  const int wn = wid & 1;         // 0..1 -> rows [wn*4, +4)
  const int l15 = lane & 15;
  const int kgrp = lane >> 4;     // 0..3
  const int l7 = l15 & 7;

  // loop-invariant address bases
  int arow[4];
  #pragma unroll
  for (int mi = 0; mi < 4; ++mi) arow[mi] = (wm*64 + mi*16 + l15) * 128;

  // B(s0) address helper: tap -> base pointer (g = kgrp)
  auto bb_s0 = [&](int tap) -> const char* {
    int kh = tap / 3, kw = tap - (tap/3)*3;
    int lk = l15 + kw;
    return sx + (4*wn + kh)*ROWB + lk*128 + ((kgrp ^ (lk & 7)) << 4);
  };

  f32x4 acc[4][8] = {};
  short8 bf[8];

  stage_x(0);
  stage_w(0, 0);
  __syncthreads();

  // prologue: preload B(st=0, s=0)
  {
    const char* bb = bb_s0(0);
    #pragma unroll
    for (int r = 0; r < 4; ++r) {
      bf[2*r]   = *(const short8*)(bb + r*ROWB);
      bf[2*r+1] = *(const short8*)(bb + 2048 + r*ROWB);
    }
  }

  for (int st = 0; st < 18; ++st) {          // 2 cin-halves x 9 taps
    const int tap = st % 9;
    const int kh = tap / 3, kw = tap - (tap/3)*3;
    const char* swb = sw + (st & 1) * WB;

    // ---- s0: A reads (the only barrier-dependent reads) ----
    short8 a[4];
    {
      const int akey = (kgrp ^ l7) << 4;     // g = kgrp
      #pragma unroll
      for (int mi = 0; mi < 4; ++mi)
        a[mi] = *(const short8*)(swb + akey + arow[mi]);
    }
    if (st + 1 < 18) stage_w(st + 1, (st + 1) & 1);  // w-DMA off crit path

    __builtin_amdgcn_s_setprio(1);
    #pragma unroll
    for (int ni = 0; ni < 8; ++ni)           // ni-major: bf[ni] dies early
      #pragma unroll
      for (int mi = 0; mi < 4; ++mi)
        acc[mi][ni] = __builtin_amdgcn_mfma_f32_16x16x32_bf16(
            a[mi], bf[ni], acc[mi][ni], 0, 0, 0);
    __builtin_amdgcn_s_setprio(0);

    // ---- s1: B + A reads (g = 4+kgrp), then cluster1 ----
    {
      const int g = 4 + kgrp;
      const int lk = l15 + kw;
      const char* bb = sx + (4*wn + kh)*ROWB + lk*128 + ((g ^ (lk & 7)) << 4);
      #pragma unroll
      for (int r = 0; r < 4; ++r) {
        bf[2*r]   = *(const short8*)(bb + r*ROWB);
        bf[2*r+1] = *(const short8*)(bb + 2048 + r*ROWB);
      }
      const int akey = (g ^ l7) << 4;
      #pragma unroll
      for (int mi = 0; mi < 4; ++mi)
        a[mi] = *(const short8*)(swb + akey + arow[mi]);
    }
    __builtin_amdgcn_s_setprio(1);
    #pragma unroll
    for (int ni = 0; ni < 8; ++ni)           // ni-major: bf[ni] dies early
      #pragma unroll
      for (int mi = 0; mi < 4; ++mi)
        acc[mi][ni] = __builtin_amdgcn_mfma_f32_16x16x32_bf16(
            a[mi], bf[ni], acc[mi][ni], 0, 0, 0);
    __builtin_amdgcn_s_setprio(0);

    // ---- pre-barrier B(s0) prefetch for next stage (zero extra regs) ----
    if (st == 8) {
      __syncthreads();      // x half-0 readers done; w(9) DMA drained here
      stage_x(1);
      __syncthreads();      // drains x half-1 DMA
      const char* bb = bb_s0(0);             // st=9 -> tap 0, new half
      #pragma unroll
      for (int r = 0; r < 4; ++r) {
        bf[2*r]   = *(const short8*)(bb + r*ROWB);
        bf[2*r+1] = *(const short8*)(bb + 2048 + r*ROWB);
      }
    } else {
      if (st + 1 < 18) {
        const char* bb = bb_s0((st + 1) % 9);
        #pragma unroll
        for (int r = 0; r < 4; ++r) {
          bf[2*r]   = *(const short8*)(bb + r*ROWB);
          bf[2*r+1] = *(const short8*)(bb + 2048 + r*ROWB);
        }
      }
      __syncthreads();      // w(st+1) staged + prefetch completed into regs
    }
  }

  // ---- epilogue: C layout col=l15 (px), row=4*kgrp+r (cout) [m89] ----
  float* ob = out + (size_t)b * COUT * (OH*OW);
  #pragma unroll
  for (int ni = 0; ni < 8; ++ni) {
    int oh = h0 + 4*wn + (ni >> 1);
    int ow = w0 + (ni & 1)*16 + l15;
    if (oh < OH && ow < OW) {
      #pragma unroll
      for (int mi = 0; mi < 4; ++mi) {
        #pragma unroll
        for (int r = 0; r < 4; ++r) {
          int cout = cblk*128 + wm*64 + mi*16 + kgrp*4 + r;
          ob[(size_t)cout*(OH*OW) + oh*OW + ow] = acc[mi][ni][r];
        }
      }
    }
  }
}

// one-time weight transpose+cvt: wt[tap][cout][cin] bf16; also zeros the
// 256-B zero page that follows wt in the workspace.
__global__ void wprep(const float* __restrict__ wgt, short* __restrict__ wt,
                      short* __restrict__ zp) {
  int idx = blockIdx.x * 256 + threadIdx.x;
  if (idx < 128) zp[idx] = 0;
  if (idx >= KHW*COUT*CIN) return;
  int khw  = idx / (COUT*CIN);
  int rem  = idx - khw*(COUT*CIN);
  int cout = rem >> 7, cin = rem & 127;
  wt[idx] = f2b(wgt[cout*(CIN*KHW) + cin*KHW + khw]);
}

// one-time x transpose+cvt: xt[b][h][w][cin] bf16, via padded LDS tile.
__global__ __launch_bounds__(256)
void xprep(const float* __restrict__ x, short* __restrict__ xt) {
  __shared__ short lsh[CIN * 113];   // 28928 B
  const int bh = blockIdx.x;
  const int b = bh / H, h = bh - b * H;
  const float* src = x + ((size_t)b * CIN * H + h) * W;
  for (int u = threadIdx.x; u < CIN * W; u += 256) {
    int c = u / W, w = u - c * W;
    lsh[c * 113 + w] = f2b(src[(size_t)c * (H*W) + w]);
  }
  __syncthreads();
  short* dst = xt + (size_t)bh * (W * CIN);
  for (int o = threadIdx.x; o < W * CIN / 8; o += 256) {   // 1792
    int w = o >> 4, s = o & 15;
    short8 v;
    #pragma unroll
    for (int j = 0; j < 8; ++j) v[j] = lsh[(s*8 + j) * 113 + w];
    *(short8*)(dst + o * 8) = v;
  }
}

extern "C" void kernel_launch(void* const* d_in, const int* in_sizes, int n_in,
                              void* d_out, int out_size, void* d_ws, size_t ws_size,
                              hipStream_t stream) {
  const float* x   = (const float*)d_in[0];
  const float* wgt = (const float*)d_in[1];
  float* out = (float*)d_out;
  const size_t wt_bytes = (size_t)(KHW*COUT*CIN) * sizeof(short);   // 589824
  const size_t zp_bytes = 256;
  const size_t xt_bytes = (size_t)32 * H * W * CIN * sizeof(short); // 102.76 MB
  dim3 grid(3584);   // 2 cblk x 4 tw x 14 th x 32 b
  if (ws_size >= wt_bytes + zp_bytes + xt_bytes) {
    short* wt = (short*)d_ws;
    short* zp = (short*)((char*)d_ws + wt_bytes);
    short* xt = (short*)((char*)d_ws + wt_bytes + zp_bytes);
    wprep<<<(KHW*COUT*CIN + 255)/256, 256, 0, stream>>>(wgt, wt, zp);
    xprep<<<32 * H, 256, 0, stream>>>(x, xt);
    conv_main<true, true><<<grid, 256, 0, stream>>>(x, wgt, wt, xt, zp, out);
  } else if (ws_size >= wt_bytes + zp_bytes) {
    short* wt = (short*)d_ws;
    short* zp = (short*)((char*)d_ws + wt_bytes);
    wprep<<<(KHW*COUT*CIN + 255)/256, 256, 0, stream>>>(wgt, wt, zp);
    conv_main<false, true><<<grid, 256, 0, stream>>>(x, wgt, wt, nullptr, zp, out);
  } else {
    conv_main<false, false><<<grid, 256, 0, stream>>>(x, wgt, nullptr, nullptr, nullptr, out);
  }
}